// Round 17
// baseline (118.857 us; speedup 1.0000x reference)
//
#include <hip/hip_runtime.h>
#include <hip/hip_bf16.h>
#include <math.h>

#define C_DIM 256
#define T_DIM 4096
#define NHEADS 8
#define NGROUPS 8
#define NSPLIT 4
#define SRANGE (T_DIM / NSPLIT)
#define NT (SRANGE / 64)

typedef __attribute__((ext_vector_type(8))) short bf16x8;
typedef __attribute__((ext_vector_type(4))) float f32x4;

#if __has_builtin(__builtin_amdgcn_exp2f)
#define EXP2(x) __builtin_amdgcn_exp2f(x)
#else
#define EXP2(x) exp2f(x)
#endif

#define MFMA16(a, b, c) __builtin_amdgcn_mfma_f32_16x16x32_bf16(a, b, c, 0, 0, 0)

// ws layout (float offsets)
#define WS_PSUM 0
#define WS_PSQ  256
#define WS_QT_F   1024
#define WS_KT_F   (WS_QT_F + 524288)
#define WS_VB_F   (WS_KT_F + 524288)
#define WS_WQB_F  (WS_VB_F + 524288)
#define WS_WPB_F  (WS_WQB_F + 98304)
#define WS_OP_F   (WS_WPB_F + 32768)                       // bf16 [z][t][256]: NSPLIT*4096*256 ushorts
#define WS_L_F    (WS_OP_F + NSPLIT * T_DIM * 256 / 2)     // fp32: NSPLIT*8*4096

// scale folded into Q: (1/sqrt(32)) * log2(e)
#define QSCALE 0.2550348527f

__device__ __forceinline__ ushort f2bf(float f) {
  union { float f; unsigned u; } v; v.f = f;
  return (ushort)((v.u + 0x7fffu + ((v.u >> 16) & 1u)) >> 16);
}

__device__ __forceinline__ float bf2f(ushort u) {
  union { unsigned u; float f; } v; v.u = ((unsigned)u) << 16;
  return v.f;
}

__device__ __forceinline__ uint pk2(float a, float b) {
  __hip_bfloat162 h = __float22bfloat162_rn(make_float2(a, b));
  union { __hip_bfloat162 h; uint u; } c; c.h = h; return c.u;
}

// ---------------- prep: weight fp32->bf16 + GroupNorm partial stats ----------------
__global__ __launch_bounds__(256) void prep(const float* __restrict__ x,
                                            const float* __restrict__ wq,
                                            const float* __restrict__ wp,
                                            float* __restrict__ ws,
                                            ushort* __restrict__ wqb,
                                            ushort* __restrict__ wpb) {
  const int i4 = (blockIdx.x * 256 + threadIdx.x) * 4;
  const int n1 = 768 * 256;
  if (i4 < n1) {
    float4 v = *(const float4*)(wq + i4);
    union { ushort us[4]; uint2 u; } pk;
    pk.us[0] = f2bf(v.x); pk.us[1] = f2bf(v.y); pk.us[2] = f2bf(v.z); pk.us[3] = f2bf(v.w);
    *(uint2*)(wqb + i4) = pk.u;
  } else {
    const int j = i4 - n1;
    float4 v = *(const float4*)(wp + j);
    union { ushort us[4]; uint2 u; } pk;
    pk.us[0] = f2bf(v.x); pk.us[1] = f2bf(v.y); pk.us[2] = f2bf(v.z); pk.us[3] = f2bf(v.w);
    *(uint2*)(wpb + j) = pk.u;
  }
  const int g = blockIdx.x >> 5;
  const int bx = blockIdx.x & 31;
  const size_t base = (size_t)g * 131072 + (size_t)bx * 4096;
  float s = 0.f, s2 = 0.f;
  for (int i = threadIdx.x; i < 4096; i += 256) {
    float v = x[base + i];
    s += v;
    s2 += v * v;
  }
#pragma unroll
  for (int mask = 1; mask <= 32; mask <<= 1) {
    s += __shfl_xor(s, mask, 64);
    s2 += __shfl_xor(s2, mask, 64);
  }
  __shared__ float red[8];
  const int wid = threadIdx.x >> 6;
  if ((threadIdx.x & 63) == 0) { red[wid] = s; red[4 + wid] = s2; }
  __syncthreads();
  if (threadIdx.x == 0) {
    ws[WS_PSUM + g * 32 + bx] = red[0] + red[1] + red[2] + red[3];
    ws[WS_PSQ + g * 32 + bx] = red[4] + red[5] + red[6] + red[7];
  }
}

// ---------------- QKV GEMM: grid(256,3) type-split; q/k via LDS transpose ----------------
__global__ __launch_bounds__(256) void qkv_mfma(const float* __restrict__ x,
                                                const float* __restrict__ gamma,
                                                const float* __restrict__ beta,
                                                const float* __restrict__ ws,
                                                const ushort* __restrict__ wqb,
                                                const float* __restrict__ bias,
                                                ushort* __restrict__ qt,
                                                ushort* __restrict__ kt,
                                                ushort* __restrict__ vb) {
  const int t0 = blockIdx.x * 16;
  const int oc = blockIdx.y;           // 0=q, 1=k, 2=v
  __shared__ ushort A[16 * 256];
  __shared__ float fg[256], fb[256];
  __shared__ float sm_stat[16];        // mean[0..7], rstd[8..15]
  const int tid = threadIdx.x;
  {
    const int gg = tid >> 5, i = tid & 31;
    float s = ws[WS_PSUM + gg * 32 + i];
    float s2 = ws[WS_PSQ + gg * 32 + i];
#pragma unroll
    for (int mask = 1; mask <= 16; mask <<= 1) {
      s += __shfl_xor(s, mask, 32);
      s2 += __shfl_xor(s2, mask, 32);
    }
    if (i == 0) {
      const float inv_n = 1.0f / 131072.0f;
      float mean = s * inv_n;
      float var = s2 * inv_n - mean * mean;
      sm_stat[gg] = mean;
      sm_stat[8 + gg] = rsqrtf(var + 1e-5f);
    }
  }
  __syncthreads();
  {
    const int c = tid, gg = c >> 5;
    float fgv = gamma[c] * sm_stat[8 + gg];
    fg[c] = fgv; fb[c] = beta[c] - sm_stat[gg] * fgv;
  }
  __syncthreads();
#pragma unroll
  for (int p = 0; p < 4; ++p) {
    const int idx = p * 256 + tid;
    const int c = idx >> 2;
    const int tin = (idx & 3) * 4;
    float4 xv = *(const float4*)(x + (size_t)c * T_DIM + t0 + tin);
    const float fgc = fg[c], fbc = fb[c];
    float xn[4] = {fmaf(xv.x, fgc, fbc), fmaf(xv.y, fgc, fbc),
                   fmaf(xv.z, fgc, fbc), fmaf(xv.w, fgc, fbc)};
#pragma unroll
    for (int i = 0; i < 4; ++i) {
      const int t = tin + i;
      A[t * 256 + (c ^ ((t & 7) << 3))] = f2bf(xn[i]);
    }
  }
  __syncthreads();

  const int w = tid >> 6, lane = tid & 63, l15 = lane & 15, g = lane >> 4;
  const int o_loc = w * 64;            // local o within this type's 256
  f32x4 acc[4] = {};
  const ushort* wrow[4];
#pragma unroll
  for (int j = 0; j < 4; ++j)
    wrow[j] = wqb + (size_t)(oc * 256 + o_loc + j * 16 + l15) * 256;

  bf16x8 bc[4], bn[4];
#pragma unroll
  for (int j = 0; j < 4; ++j) bc[j] = *(const bf16x8*)(wrow[j] + 8 * g);

#pragma unroll
  for (int kk = 0; kk < 8; ++kk) {
    const bf16x8 af = *(const bf16x8*)(&A[l15 * 256 + ((kk * 32 + 8 * g) ^ ((l15 & 7) << 3))]);
    if (kk < 7) {
#pragma unroll
      for (int j = 0; j < 4; ++j) bn[j] = *(const bf16x8*)(wrow[j] + (kk + 1) * 32 + 8 * g);
    }
#pragma unroll
    for (int j = 0; j < 4; ++j)
      acc[j] = MFMA16(af, bc[j], acc[j]);
#pragma unroll
    for (int j = 0; j < 4; ++j) bc[j] = bn[j];
  }

  if (oc == 2) {
    // V: direct [c][t] stores, 8B granules
#pragma unroll
    for (int j = 0; j < 4; ++j) {
      const int o = o_loc + j * 16 + l15;
      const float bo = bias[512 + o];
      union { ushort us[4]; uint2 u; } pk;
#pragma unroll
      for (int r = 0; r < 4; ++r) pk.us[r] = f2bf(acc[j][r] + bo);
      *(uint2*)(vb + (size_t)o * T_DIM + t0 + 4 * g) = pk.u;
    }
  } else {
    // Q/K: transpose via LDS (reuse A), then coalesced uint4 stores
    const float scale = (oc == 0) ? QSCALE : 1.0f;
    __syncthreads();   // all waves done reading A
#pragma unroll
    for (int j = 0; j < 4; ++j) {
      const int o = o_loc + j * 16 + l15;
      const float bo = bias[oc * 256 + o];
#pragma unroll
      for (int r = 0; r < 4; ++r) {
        const int t = 4 * g + r;
        A[t * 256 + (o ^ ((t & 7) << 3))] = f2bf((acc[j][r] + bo) * scale);
      }
    }
    __syncthreads();
    ushort* dst = (oc == 0) ? qt : kt;
    const int hh = tid >> 5;           // 0..7
    const int tt = (tid >> 1) & 15;    // 0..15
    const int d0 = (tid & 1) * 16;     // 0 or 16
    const int sw = (tt & 7) << 3;
    uint4 v0 = *(uint4*)&A[tt * 256 + ((hh * 32 + d0) ^ sw)];
    uint4 v1 = *(uint4*)&A[tt * 256 + ((hh * 32 + d0 + 8) ^ sw)];
    ushort* gp = dst + ((size_t)hh * T_DIM + t0 + tt) * 32 + d0;
    *(uint4*)gp = v0;
    *(uint4*)(gp + 8) = v1;
  }
}

// Per-tile attention body, macro-expanded (NO lambda: R16's lambda failed to
// inline -> scratch spills, 273MB WRITE). Transients scoped so they die.
#define TILE_BODY(KB, VB)                                                        \
  {                                                                              \
    const ushort* kbase = (KB);                                                  \
    const ushort* vbase = (VB);                                                  \
    const f32x4 z4 = {};                                                         \
    f32x4 sa0, sa1, sa2, sa3, sb0, sb1, sb2, sb3;                                \
    {                                                                            \
      const bf16x8 kf0 = *(const bf16x8*)(kbase + (0 * 16 + l15) * 40 + 8 * g);  \
      const bf16x8 kf1 = *(const bf16x8*)(kbase + (1 * 16 + l15) * 40 + 8 * g);  \
      const bf16x8 kf2 = *(const bf16x8*)(kbase + (2 * 16 + l15) * 40 + 8 * g);  \
      const bf16x8 kf3 = *(const bf16x8*)(kbase + (3 * 16 + l15) * 40 + 8 * g);  \
      __builtin_amdgcn_s_setprio(1);                                             \
      sa0 = MFMA16(kf0, qfa, z4);                                                \
      sa1 = MFMA16(kf1, qfa, z4);                                                \
      sa2 = MFMA16(kf2, qfa, z4);                                                \
      sa3 = MFMA16(kf3, qfa, z4);                                                \
      sb0 = MFMA16(kf0, qfb, z4);                                                \
      sb1 = MFMA16(kf1, qfb, z4);                                                \
      sb2 = MFMA16(kf2, qfb, z4);                                                \
      sb3 = MFMA16(kf3, qfb, z4);                                                \
      __builtin_amdgcn_s_setprio(0);                                             \
    }                                                                            \
    const bf16x8 vf00 = *(const bf16x8*)(vbase + (l15) * 72 + 8 * g);            \
    const bf16x8 vf01 = *(const bf16x8*)(vbase + (l15) * 72 + 32 + 8 * g);       \
    const bf16x8 vf10 = *(const bf16x8*)(vbase + (16 + l15) * 72 + 8 * g);       \
    const bf16x8 vf11 = *(const bf16x8*)(vbase + (16 + l15) * 72 + 32 + 8 * g);  \
    union { uint u[4]; bf16x8 v; } fa0, fa1, fb0, fb1;                           \
    {                                                                            \
      float p0, p1, p2, p3, p4, p5, p6, p7;                                      \
      p0 = EXP2(sa0[0]); p1 = EXP2(sa0[1]); p2 = EXP2(sa0[2]); p3 = EXP2(sa0[3]);\
      p4 = EXP2(sa1[0]); p5 = EXP2(sa1[1]); p6 = EXP2(sa1[2]); p7 = EXP2(sa1[3]);\
      la += ((p0 + p1) + (p2 + p3)) + ((p4 + p5) + (p6 + p7));                   \
      fa0.u[0] = pk2(p0, p1); fa0.u[1] = pk2(p2, p3);                            \
      fa0.u[2] = pk2(p4, p5); fa0.u[3] = pk2(p6, p7);                            \
      p0 = EXP2(sa2[0]); p1 = EXP2(sa2[1]); p2 = EXP2(sa2[2]); p3 = EXP2(sa2[3]);\
      p4 = EXP2(sa3[0]); p5 = EXP2(sa3[1]); p6 = EXP2(sa3[2]); p7 = EXP2(sa3[3]);\
      la += ((p0 + p1) + (p2 + p3)) + ((p4 + p5) + (p6 + p7));                   \
      fa1.u[0] = pk2(p0, p1); fa1.u[1] = pk2(p2, p3);                            \
      fa1.u[2] = pk2(p4, p5); fa1.u[3] = pk2(p6, p7);                            \
    }                                                                            \
    __builtin_amdgcn_s_setprio(1);                                               \
    Oa0 = MFMA16(vf00, fa0.v, Oa0);                                              \
    Oa0 = MFMA16(vf01, fa1.v, Oa0);                                              \
    Oa1 = MFMA16(vf10, fa0.v, Oa1);                                              \
    Oa1 = MFMA16(vf11, fa1.v, Oa1);                                              \
    __builtin_amdgcn_s_setprio(0);                                               \
    {                                                                            \
      float p0, p1, p2, p3, p4, p5, p6, p7;                                      \
      p0 = EXP2(sb0[0]); p1 = EXP2(sb0[1]); p2 = EXP2(sb0[2]); p3 = EXP2(sb0[3]);\
      p4 = EXP2(sb1[0]); p5 = EXP2(sb1[1]); p6 = EXP2(sb1[2]); p7 = EXP2(sb1[3]);\
      lb += ((p0 + p1) + (p2 + p3)) + ((p4 + p5) + (p6 + p7));                   \
      fb0.u[0] = pk2(p0, p1); fb0.u[1] = pk2(p2, p3);                            \
      fb0.u[2] = pk2(p4, p5); fb0.u[3] = pk2(p6, p7);                            \
      p0 = EXP2(sb2[0]); p1 = EXP2(sb2[1]); p2 = EXP2(sb2[2]); p3 = EXP2(sb2[3]);\
      p4 = EXP2(sb3[0]); p5 = EXP2(sb3[1]); p6 = EXP2(sb3[2]); p7 = EXP2(sb3[3]);\
      lb += ((p0 + p1) + (p2 + p3)) + ((p4 + p5) + (p6 + p7));                   \
      fb1.u[0] = pk2(p0, p1); fb1.u[1] = pk2(p2, p3);                            \
      fb1.u[2] = pk2(p4, p5); fb1.u[3] = pk2(p6, p7);                            \
    }                                                                            \
    __builtin_amdgcn_s_setprio(1);                                               \
    Ob0 = MFMA16(vf00, fb0.v, Ob0);                                              \
    Ob0 = MFMA16(vf01, fb1.v, Ob0);                                              \
    Ob1 = MFMA16(vf10, fb0.v, Ob1);                                              \
    Ob1 = MFMA16(vf11, fb1.v, Ob1);                                              \
    __builtin_amdgcn_s_setprio(0);                                               \
  }

// ---------------- Flash attention: 2 tiles/barrier, 4 LDS buffers, P in regs ----------------
__global__ __launch_bounds__(256, 4) void attn_fwd(const ushort* __restrict__ qt,
                                                   const ushort* __restrict__ kt,
                                                   const ushort* __restrict__ vb,
                                                   ushort* __restrict__ Op,
                                                   float* __restrict__ Lb) {
  const int bid = blockIdx.x;
  const int h = bid & 7;             // XCD-pinned head
  const int inner = bid >> 3;
  const int qb = inner & 31;         // 128 q-rows per block
  const int z = inner >> 5;          // split 0..3
  const int tid = threadIdx.x;
  const int w = tid >> 6, lane = tid & 63, l15 = lane & 15, g = lane >> 4;

  __shared__ ushort Klds[4][64 * 40];     // 4 buffers, 80B rows
  __shared__ ushort Vlds[4][32 * 72];     // 4 buffers, 144B rows

  const int t_a = qb * 128 + w * 16 + l15;
  const int t_b = t_a + 64;
  const bf16x8 qfa = *(const bf16x8*)(qt + ((size_t)(h * T_DIM + t_a) * 32 + 8 * g));
  const bf16x8 qfb = *(const bf16x8*)(qt + ((size_t)(h * T_DIM + t_b) * 32 + 8 * g));

  f32x4 Oa0 = {}, Oa1 = {}, Ob0 = {}, Ob1 = {};
  float la = 0.f, lb = 0.f;

  const int sbeg = z * SRANGE;
  const int p_row = tid >> 2;                    // physical K row 0..63
  const int q5 = p_row & 31;
  const int sm_row = (p_row & 32) + 16 * ((q5 >> 2) & 1) + 4 * (q5 >> 3) + (q5 & 3);
  const ushort* kgp = kt + (size_t)h * T_DIM * 32 + (size_t)(sbeg + p_row) * 32 + (tid & 3) * 8;
  const ushort* vgp = vb + (size_t)(h * 32 + (tid >> 3)) * T_DIM + sbeg + (tid & 7) * 8;
  ushort* kw0 = &Klds[0][sm_row * 40 + (tid & 3) * 8];
  ushort* vw0 = &Vlds[0][(tid >> 3) * 72 + (tid & 7) * 8];

  // prologue: tiles 0,1 -> buffers 0,1; prefetch tiles 2,3 into regs
  *(uint4*)kw0 = *(const uint4*)kgp;
  *(uint4*)(kw0 + 2560) = *(const uint4*)(kgp + 2048);
  *(uint4*)vw0 = *(const uint4*)vgp;
  *(uint4*)(vw0 + 2304) = *(const uint4*)(vgp + 64);
  uint4 kn0 = *(const uint4*)(kgp + 2 * 2048);
  uint4 kn1 = *(const uint4*)(kgp + 3 * 2048);
  uint4 vn0 = *(const uint4*)(vgp + 2 * 64);
  uint4 vn1 = *(const uint4*)(vgp + 3 * 64);
  __syncthreads();

  int cur = 0;  // buffer pair index (0 or 1)
  for (int t = 0; t < NT; t += 2) {
    if (t + 2 < NT) {
      const int dst = (cur ^ 1) * 2;
      *(uint4*)(kw0 + dst * 2560) = kn0;
      *(uint4*)(kw0 + (dst + 1) * 2560) = kn1;
      *(uint4*)(vw0 + dst * 2304) = vn0;
      *(uint4*)(vw0 + (dst + 1) * 2304) = vn1;
      if (t + 4 < NT) {
        kn0 = *(const uint4*)(kgp + (size_t)(t + 4) * 2048);
        kn1 = *(const uint4*)(kgp + (size_t)(t + 5) * 2048);
        vn0 = *(const uint4*)(vgp + (t + 4) * 64);
        vn1 = *(const uint4*)(vgp + (t + 5) * 64);
      }
    }

    TILE_BODY(&Klds[cur * 2][0], &Vlds[cur * 2][0]);
    TILE_BODY(&Klds[cur * 2 + 1][0], &Vlds[cur * 2 + 1][0]);

    __syncthreads();
    cur ^= 1;
  }

  // Op[z][t][256c]: each qfrag's 4 acc values are consecutive c -> uint2 stores
  ushort* opz = Op + (size_t)z * T_DIM * 256;
  {
    union { ushort us[4]; uint2 u; } p0, p1;
#pragma unroll
    for (int r = 0; r < 4; ++r) { p0.us[r] = f2bf(Oa0[r]); p1.us[r] = f2bf(Oa1[r]); }
    *(uint2*)(opz + (size_t)t_a * 256 + h * 32 + 4 * g) = p0.u;
    *(uint2*)(opz + (size_t)t_a * 256 + h * 32 + 16 + 4 * g) = p1.u;
#pragma unroll
    for (int r = 0; r < 4; ++r) { p0.us[r] = f2bf(Ob0[r]); p1.us[r] = f2bf(Ob1[r]); }
    *(uint2*)(opz + (size_t)t_b * 256 + h * 32 + 4 * g) = p0.u;
    *(uint2*)(opz + (size_t)t_b * 256 + h * 32 + 16 + 4 * g) = p1.u;
  }
  la += __shfl_xor(la, 16, 64);
  la += __shfl_xor(la, 32, 64);
  lb += __shfl_xor(lb, 16, 64);
  lb += __shfl_xor(lb, 32, 64);
  if (g == 0) {
    Lb[(size_t)(z * NHEADS + h) * T_DIM + t_a] = la;
    Lb[(size_t)(z * NHEADS + h) * T_DIM + t_b] = lb;
  }
}

// ---------------- Proj GEMM: single-pass (grid 256), combine + MFMA + residual ----------------
__global__ __launch_bounds__(256) void proj_mfma(const ushort* __restrict__ Op,
                                                 const float* __restrict__ Lb,
                                                 const ushort* __restrict__ wpb,
                                                 const float* __restrict__ bias,
                                                 const float* __restrict__ x,
                                                 float* __restrict__ out) {
  const int t0 = blockIdx.x * 16;
  __shared__ ushort A[16 * 256];
  __shared__ float rinv[128];
  const int tid = threadIdx.x;
  if (tid < 128) {
    const int h = tid >> 4, tt = tid & 15;
    float l = 0.f;
#pragma unroll
    for (int zz = 0; zz < NSPLIT; ++zz)
      l += Lb[(size_t)(zz * NHEADS + h) * T_DIM + t0 + tt];
    rinv[tid] = 1.0f / l;
  }
  __syncthreads();
  // combine-stage: Op[z][t][256c] -> A[t][c^sw], uint4 granules
#pragma unroll
  for (int p = 0; p < 2; ++p) {
    const int t = p * 8 + (tid >> 5);
    const int c0 = (tid & 31) * 8;
    float a8[8] = {0.f, 0.f, 0.f, 0.f, 0.f, 0.f, 0.f, 0.f};
#pragma unroll
    for (int zz = 0; zz < NSPLIT; ++zz) {
      uint4 v = *(const uint4*)(Op + ((size_t)zz * T_DIM + t0 + t) * 256 + c0);
      const ushort* us = (const ushort*)&v;
#pragma unroll
      for (int i = 0; i < 8; ++i) a8[i] += bf2f(us[i]);
    }
    const float ri = rinv[(c0 >> 5) * 16 + t];
    union { ushort us[8]; uint4 u; } pk;
#pragma unroll
    for (int i = 0; i < 8; ++i) pk.us[i] = f2bf(a8[i] * ri);
    *(uint4*)&A[t * 256 + (c0 ^ ((t & 7) << 3))] = pk.u;
  }
  __syncthreads();

  const int w = tid >> 6, lane = tid & 63, l15 = lane & 15, g = lane >> 4;
  const int o0 = w * 64;
  f32x4 acc[4] = {};
  const ushort* wrow[4];
#pragma unroll
  for (int j = 0; j < 4; ++j)
    wrow[j] = wpb + (size_t)(o0 + 16 * j + l15) * 256;

#pragma unroll
  for (int kk = 0; kk < 8; ++kk) {
    const bf16x8 af = *(const bf16x8*)(&A[l15 * 256 + ((kk * 32 + 8 * g) ^ ((l15 & 7) << 3))]);
#pragma unroll
    for (int j = 0; j < 4; ++j) {
      const bf16x8 bfr = *(const bf16x8*)(wrow[j] + kk * 32 + 8 * g);
      acc[j] = MFMA16(af, bfr, acc[j]);
    }
  }

#pragma unroll
  for (int j = 0; j < 4; ++j) {
    const int o = o0 + 16 * j + l15;
    const float bo = bias[o];
    const size_t base = (size_t)o * T_DIM + t0 + 4 * g;
    const float4 xr = *(const float4*)(x + base);
    float4 ov;
    ov.x = acc[j][0] + bo + xr.x;
    ov.y = acc[j][1] + bo + xr.y;
    ov.z = acc[j][2] + bo + xr.z;
    ov.w = acc[j][3] + bo + xr.w;
    *(float4*)(out + base) = ov;
  }
}

extern "C" void kernel_launch(void* const* d_in, const int* in_sizes, int n_in,
                              void* d_out, int out_size, void* d_ws, size_t ws_size,
                              hipStream_t stream) {
  const float* x      = (const float*)d_in[0];
  const float* gamma  = (const float*)d_in[1];
  const float* beta   = (const float*)d_in[2];
  const float* qkv_w  = (const float*)d_in[3];
  const float* qkv_b  = (const float*)d_in[4];
  const float* proj_w = (const float*)d_in[5];
  const float* proj_b = (const float*)d_in[6];
  float* out = (float*)d_out;
  float* ws  = (float*)d_ws;

  ushort* qt  = (ushort*)(ws + WS_QT_F);
  ushort* kt  = (ushort*)(ws + WS_KT_F);
  ushort* vb  = (ushort*)(ws + WS_VB_F);
  ushort* wqb = (ushort*)(ws + WS_WQB_F);
  ushort* wpb = (ushort*)(ws + WS_WPB_F);
  ushort* Op  = (ushort*)(ws + WS_OP_F);
  float*  Lb  = ws + WS_L_F;

  prep<<<256, 256, 0, stream>>>(x, qkv_w, proj_w, ws, wqb, wpb);
  qkv_mfma<<<dim3(256, 3), 256, 0, stream>>>(x, gamma, beta, ws, wqb, qkv_b, qt, kt, vb);
  attn_fwd<<<NHEADS * 32 * NSPLIT, 256, 0, stream>>>(qt, kt, vb, Op, Lb);
  proj_mfma<<<256, 256, 0, stream>>>(Op, Lb, wpb, proj_b, x, out);
}

// Round 18
// 66.509 us; speedup vs baseline: 1.7871x; 1.7871x over previous
//
#include <hip/hip_runtime.h>
#include <hip/hip_bf16.h>
#include <math.h>

#define C_DIM 256
#define T_DIM 4096
#define NHEADS 8
#define NGROUPS 8
#define NSPLIT 4
#define SRANGE (T_DIM / NSPLIT)
#define NT (SRANGE / 64)

typedef __attribute__((ext_vector_type(8))) short bf16x8;
typedef __attribute__((ext_vector_type(4))) float f32x4;

#if __has_builtin(__builtin_amdgcn_exp2f)
#define EXP2(x) __builtin_amdgcn_exp2f(x)
#else
#define EXP2(x) exp2f(x)
#endif

#define MFMA16(a, b, c) __builtin_amdgcn_mfma_f32_16x16x32_bf16(a, b, c, 0, 0, 0)

// ws layout (float offsets)
#define WS_PSUM 0
#define WS_PSQ  256
#define WS_QT_F   1024
#define WS_KT_F   (WS_QT_F + 524288)
#define WS_VB_F   (WS_KT_F + 524288)
#define WS_WQB_F  (WS_VB_F + 524288)
#define WS_WPB_F  (WS_WQB_F + 98304)
#define WS_OP_F   (WS_WPB_F + 32768)                       // bf16 [z][t][256]: NSPLIT*4096*256 ushorts
#define WS_L_F    (WS_OP_F + NSPLIT * T_DIM * 256 / 2)     // fp32: NSPLIT*8*4096

// scale folded into Q: (1/sqrt(32)) * log2(e)
#define QSCALE 0.2550348527f

__device__ __forceinline__ ushort f2bf(float f) {
  union { float f; unsigned u; } v; v.f = f;
  return (ushort)((v.u + 0x7fffu + ((v.u >> 16) & 1u)) >> 16);
}

__device__ __forceinline__ float bf2f(ushort u) {
  union { unsigned u; float f; } v; v.u = ((unsigned)u) << 16;
  return v.f;
}

__device__ __forceinline__ uint pk2(float a, float b) {
  __hip_bfloat162 h = __float22bfloat162_rn(make_float2(a, b));
  union { __hip_bfloat162 h; uint u; } c; c.h = h; return c.u;
}

// ---------------- prep: weight fp32->bf16 + GroupNorm partial stats ----------------
__global__ __launch_bounds__(256) void prep(const float* __restrict__ x,
                                            const float* __restrict__ wq,
                                            const float* __restrict__ wp,
                                            float* __restrict__ ws,
                                            ushort* __restrict__ wqb,
                                            ushort* __restrict__ wpb) {
  const int i4 = (blockIdx.x * 256 + threadIdx.x) * 4;
  const int n1 = 768 * 256;
  if (i4 < n1) {
    float4 v = *(const float4*)(wq + i4);
    union { ushort us[4]; uint2 u; } pk;
    pk.us[0] = f2bf(v.x); pk.us[1] = f2bf(v.y); pk.us[2] = f2bf(v.z); pk.us[3] = f2bf(v.w);
    *(uint2*)(wqb + i4) = pk.u;
  } else {
    const int j = i4 - n1;
    float4 v = *(const float4*)(wp + j);
    union { ushort us[4]; uint2 u; } pk;
    pk.us[0] = f2bf(v.x); pk.us[1] = f2bf(v.y); pk.us[2] = f2bf(v.z); pk.us[3] = f2bf(v.w);
    *(uint2*)(wpb + j) = pk.u;
  }
  const int g = blockIdx.x >> 5;
  const int bx = blockIdx.x & 31;
  const size_t base = (size_t)g * 131072 + (size_t)bx * 4096;
  float s = 0.f, s2 = 0.f;
  for (int i = threadIdx.x; i < 4096; i += 256) {
    float v = x[base + i];
    s += v;
    s2 += v * v;
  }
#pragma unroll
  for (int mask = 1; mask <= 32; mask <<= 1) {
    s += __shfl_xor(s, mask, 64);
    s2 += __shfl_xor(s2, mask, 64);
  }
  __shared__ float red[8];
  const int wid = threadIdx.x >> 6;
  if ((threadIdx.x & 63) == 0) { red[wid] = s; red[4 + wid] = s2; }
  __syncthreads();
  if (threadIdx.x == 0) {
    ws[WS_PSUM + g * 32 + bx] = red[0] + red[1] + red[2] + red[3];
    ws[WS_PSQ + g * 32 + bx] = red[4] + red[5] + red[6] + red[7];
  }
}

// ---------------- QKV GEMM: grid(256,3) type-split; q/k via LDS transpose ----------------
__global__ __launch_bounds__(256) void qkv_mfma(const float* __restrict__ x,
                                                const float* __restrict__ gamma,
                                                const float* __restrict__ beta,
                                                const float* __restrict__ ws,
                                                const ushort* __restrict__ wqb,
                                                const float* __restrict__ bias,
                                                ushort* __restrict__ qt,
                                                ushort* __restrict__ kt,
                                                ushort* __restrict__ vb) {
  const int t0 = blockIdx.x * 16;
  const int oc = blockIdx.y;           // 0=q, 1=k, 2=v
  __shared__ ushort A[16 * 256];
  __shared__ float fg[256], fb[256];
  __shared__ float sm_stat[16];        // mean[0..7], rstd[8..15]
  const int tid = threadIdx.x;
  {
    const int gg = tid >> 5, i = tid & 31;
    float s = ws[WS_PSUM + gg * 32 + i];
    float s2 = ws[WS_PSQ + gg * 32 + i];
#pragma unroll
    for (int mask = 1; mask <= 16; mask <<= 1) {
      s += __shfl_xor(s, mask, 32);
      s2 += __shfl_xor(s2, mask, 32);
    }
    if (i == 0) {
      const float inv_n = 1.0f / 131072.0f;
      float mean = s * inv_n;
      float var = s2 * inv_n - mean * mean;
      sm_stat[gg] = mean;
      sm_stat[8 + gg] = rsqrtf(var + 1e-5f);
    }
  }
  __syncthreads();
  {
    const int c = tid, gg = c >> 5;
    float fgv = gamma[c] * sm_stat[8 + gg];
    fg[c] = fgv; fb[c] = beta[c] - sm_stat[gg] * fgv;
  }
  __syncthreads();
#pragma unroll
  for (int p = 0; p < 4; ++p) {
    const int idx = p * 256 + tid;
    const int c = idx >> 2;
    const int tin = (idx & 3) * 4;
    float4 xv = *(const float4*)(x + (size_t)c * T_DIM + t0 + tin);
    const float fgc = fg[c], fbc = fb[c];
    float xn[4] = {fmaf(xv.x, fgc, fbc), fmaf(xv.y, fgc, fbc),
                   fmaf(xv.z, fgc, fbc), fmaf(xv.w, fgc, fbc)};
#pragma unroll
    for (int i = 0; i < 4; ++i) {
      const int t = tin + i;
      A[t * 256 + (c ^ ((t & 7) << 3))] = f2bf(xn[i]);
    }
  }
  __syncthreads();

  const int w = tid >> 6, lane = tid & 63, l15 = lane & 15, g = lane >> 4;
  const int o_loc = w * 64;            // local o within this type's 256
  f32x4 acc[4] = {};
  const ushort* wrow[4];
#pragma unroll
  for (int j = 0; j < 4; ++j)
    wrow[j] = wqb + (size_t)(oc * 256 + o_loc + j * 16 + l15) * 256;

  bf16x8 bc[4], bn[4];
#pragma unroll
  for (int j = 0; j < 4; ++j) bc[j] = *(const bf16x8*)(wrow[j] + 8 * g);

#pragma unroll
  for (int kk = 0; kk < 8; ++kk) {
    const bf16x8 af = *(const bf16x8*)(&A[l15 * 256 + ((kk * 32 + 8 * g) ^ ((l15 & 7) << 3))]);
    if (kk < 7) {
#pragma unroll
      for (int j = 0; j < 4; ++j) bn[j] = *(const bf16x8*)(wrow[j] + (kk + 1) * 32 + 8 * g);
    }
#pragma unroll
    for (int j = 0; j < 4; ++j)
      acc[j] = MFMA16(af, bc[j], acc[j]);
#pragma unroll
    for (int j = 0; j < 4; ++j) bc[j] = bn[j];
  }

  if (oc == 2) {
    // V: direct [c][t] stores, 8B granules
#pragma unroll
    for (int j = 0; j < 4; ++j) {
      const int o = o_loc + j * 16 + l15;
      const float bo = bias[512 + o];
      union { ushort us[4]; uint2 u; } pk;
#pragma unroll
      for (int r = 0; r < 4; ++r) pk.us[r] = f2bf(acc[j][r] + bo);
      *(uint2*)(vb + (size_t)o * T_DIM + t0 + 4 * g) = pk.u;
    }
  } else {
    // Q/K: transpose via LDS (reuse A), then coalesced uint4 stores
    const float scale = (oc == 0) ? QSCALE : 1.0f;
    __syncthreads();   // all waves done reading A
#pragma unroll
    for (int j = 0; j < 4; ++j) {
      const int o = o_loc + j * 16 + l15;
      const float bo = bias[oc * 256 + o];
#pragma unroll
      for (int r = 0; r < 4; ++r) {
        const int t = 4 * g + r;
        A[t * 256 + (o ^ ((t & 7) << 3))] = f2bf((acc[j][r] + bo) * scale);
      }
    }
    __syncthreads();
    ushort* dst = (oc == 0) ? qt : kt;
    const int hh = tid >> 5;           // 0..7
    const int tt = (tid >> 1) & 15;    // 0..15
    const int d0 = (tid & 1) * 16;     // 0 or 16
    const int sw = (tt & 7) << 3;
    uint4 v0 = *(uint4*)&A[tt * 256 + ((hh * 32 + d0) ^ sw)];
    uint4 v1 = *(uint4*)&A[tt * 256 + ((hh * 32 + d0 + 8) ^ sw)];
    ushort* gp = dst + ((size_t)hh * T_DIM + t0 + tt) * 32 + d0;
    *(uint4*)gp = v0;
    *(uint4*)(gp + 8) = v1;
  }
}

// ---------------- Flash attention: NSPLIT=4, P in regs, Op [z][t][256c] ----------------
__global__ __launch_bounds__(256, 4) void attn_fwd(const ushort* __restrict__ qt,
                                                   const ushort* __restrict__ kt,
                                                   const ushort* __restrict__ vb,
                                                   ushort* __restrict__ Op,
                                                   float* __restrict__ Lb) {
  const int bid = blockIdx.x;
  const int h = bid & 7;             // XCD-pinned head
  const int inner = bid >> 3;
  const int qb = inner & 31;         // 128 q-rows per block
  const int z = inner >> 5;          // split 0..3
  const int tid = threadIdx.x;
  const int w = tid >> 6, lane = tid & 63, l15 = lane & 15, g = lane >> 4;

  __shared__ ushort Klds[2][64 * 40];     // 80B rows (16B-aligned b128)
  __shared__ ushort Vlds[2][32 * 72];     // 144B rows

  const int t_a = qb * 128 + w * 16 + l15;
  const int t_b = t_a + 64;
  const bf16x8 qfa = *(const bf16x8*)(qt + ((size_t)(h * T_DIM + t_a) * 32 + 8 * g));
  const bf16x8 qfb = *(const bf16x8*)(qt + ((size_t)(h * T_DIM + t_b) * 32 + 8 * g));

  f32x4 Oa0 = {}, Oa1 = {}, Ob0 = {}, Ob1 = {};
  float la = 0.f, lb = 0.f;

  const int sbeg = z * SRANGE;
  const int p_row = tid >> 2;                    // physical K row 0..63
  const int q5 = p_row & 31;
  const int sm_row = (p_row & 32) + 16 * ((q5 >> 2) & 1) + 4 * (q5 >> 3) + (q5 & 3);
  const ushort* kgp = kt + (size_t)h * T_DIM * 32 + (size_t)(sbeg + p_row) * 32 + (tid & 3) * 8;
  const ushort* vgp = vb + (size_t)(h * 32 + (tid >> 3)) * T_DIM + sbeg + (tid & 7) * 8;
  ushort* kw0 = &Klds[0][sm_row * 40 + (tid & 3) * 8];
  ushort* vw0 = &Vlds[0][(tid >> 3) * 72 + (tid & 7) * 8];
  {
    *(uint4*)kw0 = *(const uint4*)kgp;
    *(uint4*)vw0 = *(const uint4*)vgp;
  }
  uint4 kn = *(const uint4*)(kgp + 2048);
  uint4 vn = *(const uint4*)(vgp + 64);
  __syncthreads();

  int cur = 0;
  for (int t = 0; t < NT; ++t) {
    if (t + 1 < NT) {
      *(uint4*)(kw0 + (cur ^ 1) * (64 * 40)) = kn;
      *(uint4*)(vw0 + (cur ^ 1) * (32 * 72)) = vn;
      if (t + 2 < NT) {
        kn = *(const uint4*)(kgp + (size_t)(t + 2) * 2048);
        vn = *(const uint4*)(vgp + (t + 2) * 64);
      }
    }

    const ushort* kbase = &Klds[cur][0];
    const ushort* vbase = &Vlds[cur][0];
    const f32x4 z4 = {};
    const bf16x8 kf0 = *(const bf16x8*)(kbase + (0 * 16 + l15) * 40 + 8 * g);
    const bf16x8 kf1 = *(const bf16x8*)(kbase + (1 * 16 + l15) * 40 + 8 * g);
    const bf16x8 kf2 = *(const bf16x8*)(kbase + (2 * 16 + l15) * 40 + 8 * g);
    const bf16x8 kf3 = *(const bf16x8*)(kbase + (3 * 16 + l15) * 40 + 8 * g);
    __builtin_amdgcn_s_setprio(1);
    f32x4 sa0 = MFMA16(kf0, qfa, z4);
    f32x4 sa1 = MFMA16(kf1, qfa, z4);
    f32x4 sa2 = MFMA16(kf2, qfa, z4);
    f32x4 sa3 = MFMA16(kf3, qfa, z4);
    f32x4 sb0 = MFMA16(kf0, qfb, z4);
    f32x4 sb1 = MFMA16(kf1, qfb, z4);
    f32x4 sb2 = MFMA16(kf2, qfb, z4);
    f32x4 sb3 = MFMA16(kf3, qfb, z4);
    __builtin_amdgcn_s_setprio(0);

    const bf16x8 vf00 = *(const bf16x8*)(vbase + (l15) * 72 + 8 * g);
    const bf16x8 vf01 = *(const bf16x8*)(vbase + (l15) * 72 + 32 + 8 * g);
    const bf16x8 vf10 = *(const bf16x8*)(vbase + (16 + l15) * 72 + 8 * g);
    const bf16x8 vf11 = *(const bf16x8*)(vbase + (16 + l15) * 72 + 32 + 8 * g);

    // softmax a: no-max exp2 (scores bounded, see R5), PV B-frags built in-register
    union { uint u[4]; bf16x8 v; } fa0, fa1, fb0, fb1;
    {
      float p0, p1, p2, p3, p4, p5, p6, p7;
      p0 = EXP2(sa0[0]); p1 = EXP2(sa0[1]); p2 = EXP2(sa0[2]); p3 = EXP2(sa0[3]);
      p4 = EXP2(sa1[0]); p5 = EXP2(sa1[1]); p6 = EXP2(sa1[2]); p7 = EXP2(sa1[3]);
      la += ((p0 + p1) + (p2 + p3)) + ((p4 + p5) + (p6 + p7));
      fa0.u[0] = pk2(p0, p1); fa0.u[1] = pk2(p2, p3);
      fa0.u[2] = pk2(p4, p5); fa0.u[3] = pk2(p6, p7);
      p0 = EXP2(sa2[0]); p1 = EXP2(sa2[1]); p2 = EXP2(sa2[2]); p3 = EXP2(sa2[3]);
      p4 = EXP2(sa3[0]); p5 = EXP2(sa3[1]); p6 = EXP2(sa3[2]); p7 = EXP2(sa3[3]);
      la += ((p0 + p1) + (p2 + p3)) + ((p4 + p5) + (p6 + p7));
      fa1.u[0] = pk2(p0, p1); fa1.u[1] = pk2(p2, p3);
      fa1.u[2] = pk2(p4, p5); fa1.u[3] = pk2(p6, p7);
    }

    __builtin_amdgcn_s_setprio(1);
    Oa0 = MFMA16(vf00, fa0.v, Oa0);
    Oa0 = MFMA16(vf01, fa1.v, Oa0);
    Oa1 = MFMA16(vf10, fa0.v, Oa1);
    Oa1 = MFMA16(vf11, fa1.v, Oa1);
    __builtin_amdgcn_s_setprio(0);

    // softmax b — overlaps PV-a
    {
      float p0, p1, p2, p3, p4, p5, p6, p7;
      p0 = EXP2(sb0[0]); p1 = EXP2(sb0[1]); p2 = EXP2(sb0[2]); p3 = EXP2(sb0[3]);
      p4 = EXP2(sb1[0]); p5 = EXP2(sb1[1]); p6 = EXP2(sb1[2]); p7 = EXP2(sb1[3]);
      lb += ((p0 + p1) + (p2 + p3)) + ((p4 + p5) + (p6 + p7));
      fb0.u[0] = pk2(p0, p1); fb0.u[1] = pk2(p2, p3);
      fb0.u[2] = pk2(p4, p5); fb0.u[3] = pk2(p6, p7);
      p0 = EXP2(sb2[0]); p1 = EXP2(sb2[1]); p2 = EXP2(sb2[2]); p3 = EXP2(sb2[3]);
      p4 = EXP2(sb3[0]); p5 = EXP2(sb3[1]); p6 = EXP2(sb3[2]); p7 = EXP2(sb3[3]);
      lb += ((p0 + p1) + (p2 + p3)) + ((p4 + p5) + (p6 + p7));
      fb1.u[0] = pk2(p0, p1); fb1.u[1] = pk2(p2, p3);
      fb1.u[2] = pk2(p4, p5); fb1.u[3] = pk2(p6, p7);
    }

    __builtin_amdgcn_s_setprio(1);
    Ob0 = MFMA16(vf00, fb0.v, Ob0);
    Ob0 = MFMA16(vf01, fb1.v, Ob0);
    Ob1 = MFMA16(vf10, fb0.v, Ob1);
    Ob1 = MFMA16(vf11, fb1.v, Ob1);
    __builtin_amdgcn_s_setprio(0);

    __syncthreads();
    cur ^= 1;
  }

  // Op[z][t][256c]: each qfrag's 4 acc values are consecutive c -> uint2 stores
  ushort* opz = Op + (size_t)z * T_DIM * 256;
  {
    union { ushort us[4]; uint2 u; } p0, p1;
#pragma unroll
    for (int r = 0; r < 4; ++r) { p0.us[r] = f2bf(Oa0[r]); p1.us[r] = f2bf(Oa1[r]); }
    *(uint2*)(opz + (size_t)t_a * 256 + h * 32 + 4 * g) = p0.u;
    *(uint2*)(opz + (size_t)t_a * 256 + h * 32 + 16 + 4 * g) = p1.u;
#pragma unroll
    for (int r = 0; r < 4; ++r) { p0.us[r] = f2bf(Ob0[r]); p1.us[r] = f2bf(Ob1[r]); }
    *(uint2*)(opz + (size_t)t_b * 256 + h * 32 + 4 * g) = p0.u;
    *(uint2*)(opz + (size_t)t_b * 256 + h * 32 + 16 + 4 * g) = p1.u;
  }
  la += __shfl_xor(la, 16, 64);
  la += __shfl_xor(la, 32, 64);
  lb += __shfl_xor(lb, 16, 64);
  lb += __shfl_xor(lb, 32, 64);
  if (g == 0) {
    Lb[(size_t)(z * NHEADS + h) * T_DIM + t_a] = la;
    Lb[(size_t)(z * NHEADS + h) * T_DIM + t_b] = lb;
  }
}

// ---------------- Proj GEMM: single-pass (grid 256), combine + MFMA + residual ----------------
__global__ __launch_bounds__(256) void proj_mfma(const ushort* __restrict__ Op,
                                                 const float* __restrict__ Lb,
                                                 const ushort* __restrict__ wpb,
                                                 const float* __restrict__ bias,
                                                 const float* __restrict__ x,
                                                 float* __restrict__ out) {
  const int t0 = blockIdx.x * 16;
  __shared__ ushort A[16 * 256];
  __shared__ float rinv[128];
  const int tid = threadIdx.x;
  if (tid < 128) {
    const int h = tid >> 4, tt = tid & 15;
    float l = 0.f;
#pragma unroll
    for (int zz = 0; zz < NSPLIT; ++zz)
      l += Lb[(size_t)(zz * NHEADS + h) * T_DIM + t0 + tt];
    rinv[tid] = 1.0f / l;
  }
  __syncthreads();
  // combine-stage: Op[z][t][256c] -> A[t][c^sw], uint4 granules
#pragma unroll
  for (int p = 0; p < 2; ++p) {
    const int t = p * 8 + (tid >> 5);
    const int c0 = (tid & 31) * 8;
    float a8[8] = {0.f, 0.f, 0.f, 0.f, 0.f, 0.f, 0.f, 0.f};
#pragma unroll
    for (int zz = 0; zz < NSPLIT; ++zz) {
      uint4 v = *(const uint4*)(Op + ((size_t)zz * T_DIM + t0 + t) * 256 + c0);
      const ushort* us = (const ushort*)&v;
#pragma unroll
      for (int i = 0; i < 8; ++i) a8[i] += bf2f(us[i]);
    }
    const float ri = rinv[(c0 >> 5) * 16 + t];
    union { ushort us[8]; uint4 u; } pk;
#pragma unroll
    for (int i = 0; i < 8; ++i) pk.us[i] = f2bf(a8[i] * ri);
    *(uint4*)&A[t * 256 + (c0 ^ ((t & 7) << 3))] = pk.u;
  }
  __syncthreads();

  const int w = tid >> 6, lane = tid & 63, l15 = lane & 15, g = lane >> 4;
  const int o0 = w * 64;
  f32x4 acc[4] = {};
  const ushort* wrow[4];
#pragma unroll
  for (int j = 0; j < 4; ++j)
    wrow[j] = wpb + (size_t)(o0 + 16 * j + l15) * 256;

#pragma unroll
  for (int kk = 0; kk < 8; ++kk) {
    const bf16x8 af = *(const bf16x8*)(&A[l15 * 256 + ((kk * 32 + 8 * g) ^ ((l15 & 7) << 3))]);
#pragma unroll
    for (int j = 0; j < 4; ++j) {
      const bf16x8 bfr = *(const bf16x8*)(wrow[j] + kk * 32 + 8 * g);
      acc[j] = MFMA16(af, bfr, acc[j]);
    }
  }

#pragma unroll
  for (int j = 0; j < 4; ++j) {
    const int o = o0 + 16 * j + l15;
    const float bo = bias[o];
    const size_t base = (size_t)o * T_DIM + t0 + 4 * g;
    const float4 xr = *(const float4*)(x + base);
    float4 ov;
    ov.x = acc[j][0] + bo + xr.x;
    ov.y = acc[j][1] + bo + xr.y;
    ov.z = acc[j][2] + bo + xr.z;
    ov.w = acc[j][3] + bo + xr.w;
    *(float4*)(out + base) = ov;
  }
}

extern "C" void kernel_launch(void* const* d_in, const int* in_sizes, int n_in,
                              void* d_out, int out_size, void* d_ws, size_t ws_size,
                              hipStream_t stream) {
  const float* x      = (const float*)d_in[0];
  const float* gamma  = (const float*)d_in[1];
  const float* beta   = (const float*)d_in[2];
  const float* qkv_w  = (const float*)d_in[3];
  const float* qkv_b  = (const float*)d_in[4];
  const float* proj_w = (const float*)d_in[5];
  const float* proj_b = (const float*)d_in[6];
  float* out = (float*)d_out;
  float* ws  = (float*)d_ws;

  ushort* qt  = (ushort*)(ws + WS_QT_F);
  ushort* kt  = (ushort*)(ws + WS_KT_F);
  ushort* vb  = (ushort*)(ws + WS_VB_F);
  ushort* wqb = (ushort*)(ws + WS_WQB_F);
  ushort* wpb = (ushort*)(ws + WS_WPB_F);
  ushort* Op  = (ushort*)(ws + WS_OP_F);
  float*  Lb  = ws + WS_L_F;

  prep<<<256, 256, 0, stream>>>(x, qkv_w, proj_w, ws, wqb, wpb);
  qkv_mfma<<<dim3(256, 3), 256, 0, stream>>>(x, gamma, beta, ws, wqb, qkv_b, qt, kt, vb);
  attn_fwd<<<NHEADS * 32 * NSPLIT, 256, 0, stream>>>(qt, kt, vb, Op, Lb);
  proj_mfma<<<256, 256, 0, stream>>>(Op, Lb, wpb, proj_b, x, out);
}